// Round 5
// baseline (2585.668 us; speedup 1.0000x reference)
//
#include <hip/hip_runtime.h>
#include <math.h>

#define B_N 64
#define T_N 3072
#define FIN 128
#define TP 1024      // conv output length
#define COUT 64
#define HID 256
#define G4 1024      // 4*HID
#define OUT_N 10
#define NCHUNK 24
#define CHUNK_T (T_N / NCHUNK)   // 128

// Per gate-column: 128 f16x2 dwords = 32 u32x4 chunks of w_hh.
// 1024 threads, 1 col/thread, 4 waves/SIMD -> hard 128-VGPR cap. Design for it:
#define CREG 20     // chunks 0..19  -> named SSA regs (80 VGPRs)
#define CLDS 9      // chunks 20..28 -> LDS (147456 B)
#define CSTR 3      // chunks 29..31 -> streamed from L2 each step (48 KB/step)

typedef _Float16 h2_t __attribute__((ext_vector_type(2)));
typedef unsigned u32x4 __attribute__((ext_vector_type(4)));

#if defined(__has_builtin)
#if __has_builtin(__builtin_amdgcn_fdot2)
#define HAVE_FDOT2 1
#endif
#endif

__device__ __forceinline__ float fdot2(unsigned w, unsigned h, float acc) {
#ifdef HAVE_FDOT2
    return __builtin_amdgcn_fdot2(__builtin_bit_cast(h2_t, w),
                                  __builtin_bit_cast(h2_t, h), acc, false);
#else
    h2_t wv = __builtin_bit_cast(h2_t, w), hv = __builtin_bit_cast(h2_t, h);
    return acc + (float)wv.x * (float)hv.x + (float)wv.y * (float)hv.y;
#endif
}

__device__ __forceinline__ unsigned pack2(float a, float b) {
    unsigned la = (unsigned)__builtin_bit_cast(unsigned short, (_Float16)a);
    unsigned lb = (unsigned)__builtin_bit_cast(unsigned short, (_Float16)b);
    return la | (lb << 16);
}

// ---------------------------------------------------------------------------
// Pack w_hh to f16x2 chunk layout [chunk c][col] (uint4 granules), routed to
// the REG/LDS/STREAM slices, and build wihT[k][1024] fp32 for the x-GEMM.
// grid 1024 (col), 128 threads (d = packed dword).
// ---------------------------------------------------------------------------
__global__ void pack_weights(const float* __restrict__ w_ih,
                             const float* __restrict__ w_hh,
                             unsigned* __restrict__ whhR,   // [20][1024] u32x4 flat
                             unsigned* __restrict__ whhL,   // [9][1024]  u32x4 flat
                             unsigned* __restrict__ whhS,   // [3][1024]  u32x4 flat
                             float* __restrict__ wihT) {    // [64][1024]
    int col = blockIdx.x, d = threadIdx.x;   // d = 0..127
    const float* wr = w_hh + col * HID;
    unsigned p = pack2(wr[2 * d], wr[2 * d + 1]);
    int c = d >> 2, r = d & 3;
    if (c < CREG)            whhR[((c) * 1024 + col) * 4 + r] = p;
    else if (c < CREG + CLDS) whhL[((c - CREG) * 1024 + col) * 4 + r] = p;
    else                     whhS[((c - CREG - CLDS) * 1024 + col) * 4 + r] = p;
    if (d < COUT) wihT[d * 1024 + col] = w_ih[col * COUT + d];
}

// conv weight permute: wc2[j][oc], j = kk*128+ic
__global__ void prep_conv_w(const float* __restrict__ conv_w, float* __restrict__ wc2) {
    int i = blockIdx.x * 256 + threadIdx.x;
    if (i < 24576) {
        int j = i >> 6, oc = i & 63;
        int kk = j >> 7, ic = j & 127;
        wc2[i] = conv_w[(oc * 128 + ic) * 3 + kk];
    }
}

// ---------------------------------------------------------------------------
// partial sum-of-squares over time (F.normalize along dim=1)
// ---------------------------------------------------------------------------
__global__ void norm_partial(const float* __restrict__ in, float* __restrict__ part) {
    int b = blockIdx.x, ch = blockIdx.y, f = threadIdx.x;
    const float* p = in + ((size_t)b * T_N + (size_t)ch * CHUNK_T) * FIN + f;
    float s0 = 0.f, s1 = 0.f, s2 = 0.f, s3 = 0.f;
#pragma unroll
    for (int r = 0; r < CHUNK_T; r += 4) {
        float v0 = p[(r + 0) * FIN];
        float v1 = p[(r + 1) * FIN];
        float v2 = p[(r + 2) * FIN];
        float v3 = p[(r + 3) * FIN];
        s0 += v0 * v0; s1 += v1 * v1; s2 += v2 * v2; s3 += v3 * v3;
    }
    part[(b * NCHUNK + ch) * FIN + f] = (s0 + s1) + (s2 + s3);
}

// ---------------------------------------------------------------------------
// normalize + conv1d(k=3,stride=3) + bias + relu  (stride==K -> GEMM)
// ---------------------------------------------------------------------------
__global__ __launch_bounds__(256) void conv_relu(
        const float* __restrict__ in, const float* __restrict__ part,
        const float* __restrict__ wc2, const float* __restrict__ cb,
        float* __restrict__ X) {
    __shared__ __align__(16) float xs[16 * 384];
    __shared__ __align__(16) float wsh[96 * 64];
    __shared__ float invn[FIN];

    int b = blockIdx.x, tile = blockIdx.y;
    int tid = threadIdx.x;

    if (tid < FIN) {
        float s = 0.f;
#pragma unroll
        for (int c = 0; c < NCHUNK; c++) s += part[(b * NCHUNK + c) * FIN + tid];
        invn[tid] = rsqrtf(fmaxf(s, 1e-24f));
    }
    __syncthreads();

    const float* ip = in + ((size_t)b * T_N + (size_t)tile * 48) * FIN;
    for (int i = tid; i < 6144; i += 256) xs[i] = ip[i] * invn[i & 127];

    int oc = tid & 63, tq = tid >> 6;
    float acc0 = 0.f, acc1 = 0.f, acc2 = 0.f, acc3 = 0.f;
    const float* xb = xs + tq * 4 * 384;

    for (int c = 0; c < 4; c++) {
        __syncthreads();
        for (int i = tid; i < 6144; i += 256) wsh[i] = wc2[c * 6144 + i];
        __syncthreads();
#pragma unroll 8
        for (int jj = 0; jj < 96; jj += 4) {
            int j = c * 96 + jj;
            float w0 = wsh[(jj + 0) * 64 + oc];
            float w1 = wsh[(jj + 1) * 64 + oc];
            float w2 = wsh[(jj + 2) * 64 + oc];
            float w3 = wsh[(jj + 3) * 64 + oc];
            float4 x0 = *(const float4*)(xb + j);
            float4 x1 = *(const float4*)(xb + 384 + j);
            float4 x2 = *(const float4*)(xb + 768 + j);
            float4 x3 = *(const float4*)(xb + 1152 + j);
            acc0 += w0 * x0.x + w1 * x0.y + w2 * x0.z + w3 * x0.w;
            acc1 += w0 * x1.x + w1 * x1.y + w2 * x1.z + w3 * x1.w;
            acc2 += w0 * x2.x + w1 * x2.y + w2 * x2.z + w3 * x2.w;
            acc3 += w0 * x3.x + w1 * x3.y + w2 * x3.z + w3 * x3.w;
        }
    }
    float bb = cb[oc];
    int tp0 = tile * 16 + tq * 4;
    size_t o = ((size_t)b * TP + tp0) * COUT + oc;
    X[o]       = fmaxf(acc0 + bb, 0.f);
    X[o + 64]  = fmaxf(acc1 + bb, 0.f);
    X[o + 128] = fmaxf(acc2 + bb, 0.f);
    X[o + 192] = fmaxf(acc3 + bb, 0.f);
}

// ---------------------------------------------------------------------------
// x-projection GEMM: xg[b,t,j] = X[b,t,:] @ w_ih[j,:] + b_ih[j] + b_hh[j],
// stored f16. grid (64 b, 64 t-tiles of 16), 256 threads.
// ---------------------------------------------------------------------------
__global__ __launch_bounds__(256) void x_gemm(
        const float* __restrict__ X, const float* __restrict__ wihT,
        const float* __restrict__ b_ih, const float* __restrict__ b_hh,
        _Float16* __restrict__ xg) {
    __shared__ float xs[64 * 17];   // [k][r], padded
    int b = blockIdx.x, t0 = blockIdx.y * 16, tid = threadIdx.x;

    const float* Xp = X + ((size_t)b * TP + t0) * COUT;
    for (int i = tid; i < 1024; i += 256) {
        int r = i >> 6, k = i & 63;
        xs[k * 17 + r] = Xp[i];
    }
    __syncthreads();

#pragma unroll
    for (int jt = 0; jt < 4; jt++) {
        int jj = jt * 256 + tid;
        float bias = b_ih[jj] + b_hh[jj];
        float acc[16];
#pragma unroll
        for (int r = 0; r < 16; r++) acc[r] = bias;
        for (int k = 0; k < 64; k++) {
            float w = wihT[k * 1024 + jj];
#pragma unroll
            for (int r = 0; r < 16; r++) acc[r] += w * xs[k * 17 + r];
        }
#pragma unroll
        for (int r = 0; r < 16; r++)
            xg[((size_t)b * TP + t0 + r) * 1024 + jj] = (_Float16)acc[r];
    }
}

// ---------------------------------------------------------------------------
// Persistent LSTM: 64 blocks x 1024 threads (16 waves, 4/SIMD), one block/CU.
// Thread j owns ONE gate column j: i|f|g|o for j in [0,256)|[512)|[768)|[1024).
// w_hh chunks: 20 named-SSA regs + 9 LDS + 3 L2-streamed.  h f16 in LDS
// (broadcast reads). Gate exchange via LDS, activations pre-applied by the
// owning (otherwise idle) threads so the j<256 tail is short.
// ---------------------------------------------------------------------------
__device__ __forceinline__ float fsig(float x) {
    return 1.f / (1.f + __expf(-x));
}
__device__ __forceinline__ float ftanh(float x) {
    float xc = fminf(fmaxf(x, -15.f), 15.f);
    float e = __expf(2.f * xc);
    return (e - 1.f) / (e + 1.f);
}

#define SM_WL   0
#define SM_H    147456
#define SM_GSH  147968
#define SM_H32  151040
#define SM_SIZE 152064

#define REP20(M) M(0) M(1) M(2) M(3) M(4) M(5) M(6) M(7) M(8) M(9) \
                 M(10) M(11) M(12) M(13) M(14) M(15) M(16) M(17) M(18) M(19)
#define REP9(M)  M(0) M(1) M(2) M(3) M(4) M(5) M(6) M(7) M(8)

#define DECLW(n)  u32x4 wr##n;
#define LOADW(n)  wr##n = whhR4[(n) * 1024 + j];
#define DOT4(W, H) { \
    a0 = fdot2((W)[0], (H)[0], a0); a0 = fdot2((W)[1], (H)[1], a0); \
    a0 = fdot2((W)[2], (H)[2], a0); a0 = fdot2((W)[3], (H)[3], a0); }
#define DOTCH(n)  { u32x4 H = hs4[n]; DOT4(wr##n, H); }
#define DOTLDS(m) { u32x4 W = wL[(m) * 1024 + j]; u32x4 H = hs4[CREG + (m)]; DOT4(W, H); }

__global__ __attribute__((amdgpu_flat_work_group_size(1024, 1024)))
void lstm_kernel(
        const u32x4* __restrict__ whhR4, const u32x4* __restrict__ whhL4,
        const u32x4* __restrict__ whhS4,
        const _Float16* __restrict__ xg,
        const float* __restrict__ hx0, const float* __restrict__ cx0,
        const float* __restrict__ lin_w, const float* __restrict__ lin_b,
        float* __restrict__ out) {
    extern __shared__ char smem[];
    u32x4*    wL    = (u32x4*)(smem + SM_WL);       // [9][1024] uint4
    _Float16* h_s   = (_Float16*)(smem + SM_H);     // 256
    float*    gsh   = (float*)(smem + SM_GSH);      // 768: sig(f),tanh(g),sig(o)
    float*    h32_s = (float*)(smem + SM_H32);      // 256

    const int b = blockIdx.x, j = threadIdx.x;

    // named-SSA register-resident w_hh chunks (80 VGPRs)
    REP20(DECLW)
    REP20(LOADW)

    // stage LDS-resident chunks
    for (int i = j; i < CLDS * 1024; i += 1024) wL[i] = whhL4[i];

    float c_reg = 0.f;
    if (j < HID) {
        c_reg = cx0[b * HID + j];
        h_s[j] = (_Float16)hx0[b * HID + j];
    }
    const _Float16* Xg = xg + (size_t)b * TP * G4;
    _Float16 xa = Xg[j];
    __syncthreads();

    const u32x4* hs4 = (const u32x4*)h_s;   // 32 chunks of 8 h-values
    const u32x4* sP = whhS4 + j;

    for (int t = 0; t < TP; t++) {
        _Float16 xan = (_Float16)0.f;
        if (t + 1 < TP) xan = Xg[(t + 1) * G4 + j];

        // streamed weight chunks: issue early, consume at the end of the dot
        u32x4 s0 = sP[0 * 1024], s1 = sP[1 * 1024], s2 = sP[2 * 1024];

        float a0 = (float)xa;   // bias folded into xg
        REP20(DOTCH)
        REP9(DOTLDS)
        { u32x4 H = hs4[29]; DOT4(s0, H); }
        { u32x4 H = hs4[30]; DOT4(s1, H); }
        { u32x4 H = hs4[31]; DOT4(s2, H); }

        // owners of f/g/o apply their activation and publish (wave-uniform)
        if (j >= HID) {
            float v;
            if (j < 512)      v = fsig(a0);    // f
            else if (j < 768) v = ftanh(a0);   // g
            else              v = fsig(a0);    // o
            gsh[j - HID] = v;
        }
        float ig = fsig(a0);    // i (used only by j<256, divergence-free)
        __syncthreads();
        if (j < HID) {
            float fg = gsh[j], gg = gsh[HID + j], og = gsh[2 * HID + j];
            c_reg = fg * c_reg + ig * gg;
            float hh = og * ftanh(c_reg);
            h_s[j] = (_Float16)hh;
            if (t == TP - 1) h32_s[j] = hh;
        }
        __syncthreads();
        xa = xan;
    }

    // epilogue: out[b] = h @ lin_w.T + lin_b  (fp32 h)
    if (j < OUT_N) {
        float s = lin_b[j];
        const float* lw = lin_w + j * HID;
#pragma unroll 4
        for (int k = 0; k < HID; k++) s += h32_s[k] * lw[k];
        out[b * OUT_N + j] = s;
    }
}

// ---------------------------------------------------------------------------
extern "C" void kernel_launch(void* const* d_in, const int* in_sizes, int n_in,
                              void* d_out, int out_size, void* d_ws, size_t ws_size,
                              hipStream_t stream) {
    const float* input  = (const float*)d_in[0];
    // d_in[1] = r (unused)
    const float* hx0    = (const float*)d_in[2];
    const float* cx0    = (const float*)d_in[3];
    const float* conv_w = (const float*)d_in[4];
    const float* conv_b = (const float*)d_in[5];
    const float* w_ih   = (const float*)d_in[6];
    const float* b_ih   = (const float*)d_in[7];
    const float* w_hh   = (const float*)d_in[8];
    const float* b_hh   = (const float*)d_in[9];
    const float* lin_w  = (const float*)d_in[10];
    const float* lin_b  = (const float*)d_in[11];

    float* ws = (float*)d_ws;
    float*     part = ws;                       // 196608 floats
    float*     X    = part + 196608;            // 4194304 floats
    float*     wc2  = X + 4194304;              // 24576 floats
    float*     wihT = wc2 + 24576;              // 65536 floats
    unsigned*  whhR = (unsigned*)(wihT + 65536);   // 20*1024*4 dwords
    unsigned*  whhL = whhR + CREG * 1024 * 4;      // 9*1024*4 dwords
    unsigned*  whhS = whhL + CLDS * 1024 * 4;      // 3*1024*4 dwords
    _Float16*  xg   = (_Float16*)(whhS + CSTR * 1024 * 4);  // 64*1024*1024 halves

    (void)hipFuncSetAttribute((const void*)lstm_kernel,
                              hipFuncAttributeMaxDynamicSharedMemorySize, SM_SIZE);

    pack_weights<<<1024, 128, 0, stream>>>(w_ih, w_hh, whhR, whhL, whhS, wihT);
    prep_conv_w<<<96, 256, 0, stream>>>(conv_w, wc2);
    norm_partial<<<dim3(B_N, NCHUNK), FIN, 0, stream>>>(input, part);
    conv_relu<<<dim3(B_N, 64), 256, 0, stream>>>(input, part, wc2, conv_b, X);
    x_gemm<<<dim3(B_N, 64), 256, 0, stream>>>(X, wihT, b_ih, b_hh, xg);
    lstm_kernel<<<B_N, 1024, SM_SIZE, stream>>>(
        (const u32x4*)whhR, (const u32x4*)whhL, (const u32x4*)whhS, xg,
        hx0, cx0, lin_w, lin_b, (float*)d_out);
}